// Round 1
// baseline (165.925 us; speedup 1.0000x reference)
//
#include <hip/hip_runtime.h>
#include <math.h>

#define BB 8
#define SS 8192
#define DD 64
#define DM 1024
#define EPSF 1e-8f

// Flat output layout: yQ [B*S*DM] then xi [B*S]
#define YQ_ELEMS ((size_t)BB * SS * DM)

// ws layout (floats): UP[1024] | UN[1024] | DP[1024] | DN[1024]  (16 KB)

// Kernel A: precompute per-n vectors.
// UP[n] = sum_{m: W1[m]>0} W1[m]*W2[m][n]     (slope for xi > 0)
// UN[n] = sum_{m: W1[m]<0} W1[m]*W2[m][n]     (slope for xi <= 0)
// DP[n] = sum_{m: W1[m]>0} b1[m]*W2[m][n]
// DN[n] = sum_{m: W1[m]<0} b1[m]*W2[m][n]
// Grid: 32 blocks x 256 threads. Block owns n-range [blk*32, blk*32+32).
__global__ __launch_bounds__(256) void qac_precompute(
    const float* __restrict__ W1, const float* __restrict__ b1,
    const float* __restrict__ W2, float* __restrict__ ws) {
  __shared__ float red[4][8][32];
  const int t = threadIdx.x;
  const int tn = t & 31;       // n within block's range
  const int tm = t >> 5;       // 0..7 m-chunk
  const int n = blockIdx.x * 32 + tn;

  float up = 0.f, un = 0.f, dp = 0.f, dn = 0.f;
  const int m0 = tm * 128;
#pragma unroll 4
  for (int i = 0; i < 128; ++i) {
    const int m = m0 + i;
    const float w1 = W1[m];
    const float bbv = b1[m];
    const float w2 = W2[(size_t)m * DM + n];
    if (w1 > 0.f) {
      up += w1 * w2;
      dp += bbv * w2;
    } else if (w1 < 0.f) {
      un += w1 * w2;
      dn += bbv * w2;
    }
  }
  red[0][tm][tn] = up;
  red[1][tm][tn] = un;
  red[2][tm][tn] = dp;
  red[3][tm][tn] = dn;
  __syncthreads();
  if (t < 128) {
    const int q = t >> 5;
    const int tn2 = t & 31;
    float s = 0.f;
#pragma unroll
    for (int i = 0; i < 8; ++i) s += red[q][i][tn2];
    ws[q * DM + blockIdx.x * 32 + tn2] = s;
  }
}

// Kernel B: per 32-row chunk, compute xi then stream yQ rows.
// Grid: 2048 blocks x 256 threads.
__global__ __launch_bounds__(256) void qac_main(
    const float* __restrict__ psiQ, const float* __restrict__ psiK,
    const float* __restrict__ psiV, const float* __restrict__ b2,
    const float* __restrict__ ws, float* __restrict__ out) {
  __shared__ float xis[32];
  const int t = threadIdx.x;
  const int r0 = blockIdx.x * 32;  // first row of this block
  const int g = t & 15;            // lane within 16-lane row group
  const int grp = t >> 4;          // 0..15 row group

  // ---- phase 1: xi for 32 rows (16 rows per pass, 16 lanes per row) ----
#pragma unroll
  for (int pass = 0; pass < 2; ++pass) {
    const int row = r0 + pass * 16 + grp;
    const float4 q = ((const float4*)(psiQ + (size_t)row * DD))[g];
    const float4 k = ((const float4*)(psiK + (size_t)row * DD))[g];
    const float4 v = ((const float4*)(psiV + (size_t)row * DD))[g];

    float sq = q.x + q.y + q.z + q.w;
    float sq2 = q.x * q.x + q.y * q.y + q.z * q.z + q.w * q.w;
    float sk2 = k.x * k.x + k.y * k.y + k.z * k.z + k.w * k.w;
    const float v2 = v.x * v.x + v.y * v.y + v.z * v.z + v.w * v.w;
    float va = (g < 8) ? v2 : 0.f;   // d in [0,32)
    float vb = (g < 8) ? 0.f : v2;   // d in [32,64)
    const float k0 = k.x;            // valid on g==0

    // 16-lane group reduction (xor masks < 16 stay within the group)
#pragma unroll
    for (int m = 1; m < 16; m <<= 1) {
      sq  += __shfl_xor(sq, m);
      sq2 += __shfl_xor(sq2, m);
      sk2 += __shfl_xor(sk2, m);
      va  += __shfl_xor(va, m);
      vb  += __shfl_xor(vb, m);
    }
    if (g == 0) {
      const float nq = sqrtf(sq2) + EPSF;
      const float nk = sqrtf(sk2) + EPSF;
      const float nv = sqrtf(va + vb) + EPSF;
      const float sqn = sq / nq;
      const float k0n = k0 / nk;
      const float att = sqn * sqn * k0n * k0n * (1.0f / 64.0f);
      const float vexp = (va - vb) / (nv * nv);
      xis[pass * 16 + grp] = att * vexp;
    }
  }
  __syncthreads();

  // xi output
  if (t < 32) out[YQ_ELEMS + r0 + t] = xis[t];

  // ---- phase 2: yQ rows, per-n vectors in registers ----
  const float4 up = ((const float4*)(ws))[t];
  const float4 un = ((const float4*)(ws + DM))[t];
  const float4 dp = ((const float4*)(ws + 2 * DM))[t];
  const float4 dn = ((const float4*)(ws + 3 * DM))[t];
  const float4 bb = ((const float4*)b2)[t];

#pragma unroll 4
  for (int r = 0; r < 32; ++r) {
    const float xi = xis[r];
    const bool pos = xi > 0.f;
    const float4 u = pos ? up : un;
    const float4 d = pos ? dp : dn;
    float4 o;
    o.x = fmaf(xi, u.x, bb.x + d.x);
    o.y = fmaf(xi, u.y, bb.y + d.y);
    o.z = fmaf(xi, u.z, bb.z + d.z);
    o.w = fmaf(xi, u.w, bb.w + d.w);
    ((float4*)(out + (size_t)(r0 + r) * DM))[t] = o;
  }
}

extern "C" void kernel_launch(void* const* d_in, const int* in_sizes, int n_in,
                              void* d_out, int out_size, void* d_ws, size_t ws_size,
                              hipStream_t stream) {
  const float* psiQ = (const float*)d_in[0];
  const float* psiK = (const float*)d_in[1];
  const float* psiV = (const float*)d_in[2];
  const float* W1 = (const float*)d_in[3];
  const float* b1 = (const float*)d_in[4];
  const float* W2 = (const float*)d_in[5];
  const float* b2 = (const float*)d_in[6];
  float* out = (float*)d_out;
  float* ws = (float*)d_ws;

  qac_precompute<<<32, 256, 0, stream>>>(W1, b1, W2, ws);
  qac_main<<<2048, 256, 0, stream>>>(psiQ, psiK, psiV, b2, ws, out);
}

// Round 2
// 122.249 us; speedup vs baseline: 1.3573x; 1.3573x over previous
//
#include <hip/hip_runtime.h>
#include <math.h>

#define BB 8
#define SS 8192
#define DD 64
#define DM 1024
#define EPSF 1e-8f
#define NROWS (BB * SS)                 // 65536 rows
#define YQ_ELEMS ((size_t)NROWS * DM)   // yQ elements; xi follows in d_out

// ws float layout:
//   part[mb][vec][n] : 4 * 4 * 1024 floats (64 KB)   vec: 0=UP 1=UN 2=DP 3=DN
//   xi[NROWS]        : 65536 floats (256 KB)
#define PART_OFF 0
#define XI_OFF 16384

// ---------------- Kernel P: partial per-n vectors over m-chunks ----------------
// Grid 128 = 32 n-blocks x 4 m-blocks. Branchless FMA body, unroll 8.
__global__ __launch_bounds__(256) void qac_part(
    const float* __restrict__ W1, const float* __restrict__ b1,
    const float* __restrict__ W2, float* __restrict__ ws) {
  __shared__ float red[4][8][32];
  const int t = threadIdx.x;
  const int tn = t & 31;   // n within block's 32-col range
  const int tm = t >> 5;   // 0..7 m-sub-chunk
  const int nb = blockIdx.x & 31;
  const int mb = blockIdx.x >> 5;  // 0..3
  const int n = nb * 32 + tn;

  float up = 0.f, un = 0.f, dp = 0.f, dn = 0.f;
  const int m0 = mb * 256 + tm * 32;
#pragma unroll 8
  for (int i = 0; i < 32; ++i) {
    const int m = m0 + i;
    const float w1 = W1[m];
    const float bv = b1[m];
    const float w2 = W2[(size_t)m * DM + n];
    const float wp = w1 > 0.f ? w1 : 0.f;
    const float wn = w1 < 0.f ? w1 : 0.f;
    const float bp = w1 > 0.f ? bv : 0.f;
    const float bn = w1 < 0.f ? bv : 0.f;
    up = fmaf(wp, w2, up);
    un = fmaf(wn, w2, un);
    dp = fmaf(bp, w2, dp);
    dn = fmaf(bn, w2, dn);
  }
  red[0][tm][tn] = up;
  red[1][tm][tn] = un;
  red[2][tm][tn] = dp;
  red[3][tm][tn] = dn;
  __syncthreads();
  if (t < 128) {
    const int q = t >> 5;
    const int tn2 = t & 31;
    float s = 0.f;
#pragma unroll
    for (int i = 0; i < 8; ++i) s += red[q][i][tn2];
    ws[PART_OFF + (mb * 4 + q) * DM + nb * 32 + tn2] = s;
  }
}

// ---------------- Kernel X: xi only (read-bound) ----------------
// Grid 4096 x 256: 16 rows/block, 16 lanes/row.
__global__ __launch_bounds__(256) void qac_xi(
    const float* __restrict__ psiQ, const float* __restrict__ psiK,
    const float* __restrict__ psiV, float* __restrict__ ws,
    float* __restrict__ out) {
  const int t = threadIdx.x;
  const int g = t & 15;
  const int grp = t >> 4;
  const int row = blockIdx.x * 16 + grp;

  const float4 q = ((const float4*)(psiQ + (size_t)row * DD))[g];
  const float4 k = ((const float4*)(psiK + (size_t)row * DD))[g];
  const float4 v = ((const float4*)(psiV + (size_t)row * DD))[g];

  float sq = q.x + q.y + q.z + q.w;
  float sq2 = q.x * q.x + q.y * q.y + q.z * q.z + q.w * q.w;
  float sk2 = k.x * k.x + k.y * k.y + k.z * k.z + k.w * k.w;
  const float v2 = v.x * v.x + v.y * v.y + v.z * v.z + v.w * v.w;
  float va = (g < 8) ? v2 : 0.f;  // d in [0,32)
  float vb = (g < 8) ? 0.f : v2;  // d in [32,64)
  const float k0 = k.x;           // k[row][0] on lane g==0

#pragma unroll
  for (int m = 1; m < 16; m <<= 1) {
    sq += __shfl_xor(sq, m);
    sq2 += __shfl_xor(sq2, m);
    sk2 += __shfl_xor(sk2, m);
    va += __shfl_xor(va, m);
    vb += __shfl_xor(vb, m);
  }
  if (g == 0) {
    const float nq = sqrtf(sq2) + EPSF;
    const float nk = sqrtf(sk2) + EPSF;
    const float nv = sqrtf(va + vb) + EPSF;
    const float sqn = sq / nq;
    const float k0n = k0 / nk;
    const float att = sqn * sqn * k0n * k0n * (1.0f / 64.0f);
    const float vexp = (va - vb) / (nv * nv);
    const float xi = att * vexp;
    ws[XI_OFF + row] = xi;
    out[YQ_ELEMS + row] = xi;
  }
}

// ---------------- Kernel Y: pure yQ stream (write-bound, fill-like) ----------------
// Grid 2048 x 256: 32 rows/block, 128 KB contiguous stores per block.
__global__ __launch_bounds__(256) void qac_stream(
    const float* __restrict__ b2, const float* __restrict__ ws,
    float* __restrict__ out) {
  __shared__ float xis[32];
  const int t = threadIdx.x;
  const int r0 = blockIdx.x * 32;
  if (t < 32) xis[t] = ws[XI_OFF + r0 + t];

  // combine the 4 m-chunk partials (64 KB, L2-resident)
  float4 up = {0.f, 0.f, 0.f, 0.f}, un = {0.f, 0.f, 0.f, 0.f};
  float4 dp = {0.f, 0.f, 0.f, 0.f}, dn = {0.f, 0.f, 0.f, 0.f};
#pragma unroll
  for (int mb = 0; mb < 4; ++mb) {
    const float4 a = ((const float4*)(ws + (size_t)(mb * 4 + 0) * DM))[t];
    const float4 b = ((const float4*)(ws + (size_t)(mb * 4 + 1) * DM))[t];
    const float4 c = ((const float4*)(ws + (size_t)(mb * 4 + 2) * DM))[t];
    const float4 d = ((const float4*)(ws + (size_t)(mb * 4 + 3) * DM))[t];
    up.x += a.x; up.y += a.y; up.z += a.z; up.w += a.w;
    un.x += b.x; un.y += b.y; un.z += b.z; un.w += b.w;
    dp.x += c.x; dp.y += c.y; dp.z += c.z; dp.w += c.w;
    dn.x += d.x; dn.y += d.y; dn.z += d.z; dn.w += d.w;
  }
  const float4 bb = ((const float4*)b2)[t];
  float4 cp, cn;
  cp.x = bb.x + dp.x; cp.y = bb.y + dp.y; cp.z = bb.z + dp.z; cp.w = bb.w + dp.w;
  cn.x = bb.x + dn.x; cn.y = bb.y + dn.y; cn.z = bb.z + dn.z; cn.w = bb.w + dn.w;
  __syncthreads();

#pragma unroll 8
  for (int r = 0; r < 32; ++r) {
    const float xi = xis[r];
    const bool pos = xi > 0.f;
    float4 o;
    o.x = fmaf(xi, pos ? up.x : un.x, pos ? cp.x : cn.x);
    o.y = fmaf(xi, pos ? up.y : un.y, pos ? cp.y : cn.y);
    o.z = fmaf(xi, pos ? up.z : un.z, pos ? cp.z : cn.z);
    o.w = fmaf(xi, pos ? up.w : un.w, pos ? cp.w : cn.w);
    ((float4*)(out + (size_t)(r0 + r) * DM))[t] = o;
  }
}

extern "C" void kernel_launch(void* const* d_in, const int* in_sizes, int n_in,
                              void* d_out, int out_size, void* d_ws, size_t ws_size,
                              hipStream_t stream) {
  const float* psiQ = (const float*)d_in[0];
  const float* psiK = (const float*)d_in[1];
  const float* psiV = (const float*)d_in[2];
  const float* W1 = (const float*)d_in[3];
  const float* b1 = (const float*)d_in[4];
  const float* W2 = (const float*)d_in[5];
  const float* b2 = (const float*)d_in[6];
  float* out = (float*)d_out;
  float* ws = (float*)d_ws;

  qac_part<<<128, 256, 0, stream>>>(W1, b1, W2, ws);
  qac_xi<<<NROWS / 16, 256, 0, stream>>>(psiQ, psiK, psiV, ws, out);
  qac_stream<<<NROWS / 32, 256, 0, stream>>>(b2, ws, out);
}

// Round 4
// 63.982 us; speedup vs baseline: 2.5933x; 1.9107x over previous
//
#include <hip/hip_runtime.h>
#include <math.h>

#define BB 8
#define SS 8192
#define DD 64
#define DM 1024
#define EPSF 1e-8f
#define NROWS (BB * SS)                 // 65536 rows
#define YQ_ELEMS ((size_t)NROWS * DM)   // yQ elements; xi follows in d_out

#define NPBLK 64                        // P-blocks inside kernel 1

typedef float floatx4 __attribute__((ext_vector_type(4)));

// ws float layout (final vectors, 16 KB):
//   UP[1024] | UN[1024] | CP[1024]=b2+DP | CN[1024]=b2+DN

// ---------------- Kernel 1: P-blocks (0..63) + X-blocks (64..4159) ----------------
__global__ __launch_bounds__(256) void qac_prep(
    const float* __restrict__ psiQ, const float* __restrict__ psiK,
    const float* __restrict__ psiV, const float* __restrict__ W1,
    const float* __restrict__ b1, const float* __restrict__ W2,
    const float* __restrict__ b2, float* __restrict__ ws,
    float* __restrict__ out) {
  const int t = threadIdx.x;

  if (blockIdx.x < NPBLK) {
    // ---- P: final per-n vectors for 16 columns ----
    __shared__ float red[4][16][16];
    const int tn = t & 15;   // col within block's 16-col strip
    const int tm = t >> 4;   // 0..15 m-chunk (64 m each)
    const int nb = blockIdx.x;
    const int n = nb * 16 + tn;

    float up = 0.f, un = 0.f, dp = 0.f, dn = 0.f;
    const int m0 = tm * 64;
#pragma unroll 8
    for (int i = 0; i < 64; ++i) {
      const int m = m0 + i;
      const float w1 = W1[m];
      const float bv = b1[m];
      const float w2 = W2[(size_t)m * DM + n];
      const float wp = w1 > 0.f ? w1 : 0.f;
      const float wn = w1 < 0.f ? w1 : 0.f;
      const float bp = w1 > 0.f ? bv : 0.f;
      const float bn = w1 < 0.f ? bv : 0.f;
      up = fmaf(wp, w2, up);
      un = fmaf(wn, w2, un);
      dp = fmaf(bp, w2, dp);
      dn = fmaf(bn, w2, dn);
    }
    red[0][tm][tn] = up;
    red[1][tm][tn] = un;
    red[2][tm][tn] = dp;
    red[3][tm][tn] = dn;
    __syncthreads();
    if (t < 64) {
      const int q = t >> 4;        // which vector
      const int col = t & 15;
      float s = 0.f;
#pragma unroll
      for (int j = 0; j < 16; ++j) s += red[q][j][col];
      const int n2 = nb * 16 + col;
      if (q < 2) {
        ws[q * DM + n2] = s;                  // UP / UN
      } else {
        ws[q * DM + n2] = b2[n2] + s;         // CP / CN (b2 folded)
      }
    }
    return;
  }

  // ---- X: xi for 16 rows (16 lanes per row) ----
  const int g = t & 15;
  const int grp = t >> 4;
  const int row = (blockIdx.x - NPBLK) * 16 + grp;

  const float4 q = ((const float4*)(psiQ + (size_t)row * DD))[g];
  const float4 k = ((const float4*)(psiK + (size_t)row * DD))[g];
  const float4 v = ((const float4*)(psiV + (size_t)row * DD))[g];

  float sq = q.x + q.y + q.z + q.w;
  float sq2 = q.x * q.x + q.y * q.y + q.z * q.z + q.w * q.w;
  float sk2 = k.x * k.x + k.y * k.y + k.z * k.z + k.w * k.w;
  const float v2 = v.x * v.x + v.y * v.y + v.z * v.z + v.w * v.w;
  float va = (g < 8) ? v2 : 0.f;  // d in [0,32)
  float vb = (g < 8) ? 0.f : v2;  // d in [32,64)
  const float k0 = k.x;           // k[row][0] on lane g==0

#pragma unroll
  for (int m = 1; m < 16; m <<= 1) {
    sq += __shfl_xor(sq, m);
    sq2 += __shfl_xor(sq2, m);
    sk2 += __shfl_xor(sk2, m);
    va += __shfl_xor(va, m);
    vb += __shfl_xor(vb, m);
  }
  if (g == 0) {
    const float nq = sqrtf(sq2) + EPSF;
    const float nk = sqrtf(sk2) + EPSF;
    const float nv = sqrtf(va + vb) + EPSF;
    const float sqn = sq / nq;
    const float k0n = k0 / nk;
    const float att = sqn * sqn * k0n * k0n * (1.0f / 64.0f);
    const float vexp = (va - vb) / (nv * nv);
    out[YQ_ELEMS + row] = att * vexp;   // xi lives in d_out; Y reads it back
  }
}

// ---------------- Kernel Y: pure yQ stream, nontemporal ----------------
// Grid 1024 x 256: 64 rows/block, 256 KB contiguous nt-stores per block.
__global__ __launch_bounds__(256) void qac_stream(
    const float* __restrict__ ws, float* __restrict__ out) {
  __shared__ float xis[64];
  const int t = threadIdx.x;
  const int r0 = blockIdx.x * 64;
  if (t < 64) xis[t] = out[YQ_ELEMS + r0 + t];

  const float4 up = ((const float4*)(ws))[t];
  const float4 un = ((const float4*)(ws + DM))[t];
  const float4 cp = ((const float4*)(ws + 2 * DM))[t];
  const float4 cn = ((const float4*)(ws + 3 * DM))[t];
  __syncthreads();

#pragma unroll 8
  for (int r = 0; r < 64; ++r) {
    const float xi = xis[r];
    const bool pos = xi > 0.f;
    floatx4 o;
    o.x = fmaf(xi, pos ? up.x : un.x, pos ? cp.x : cn.x);
    o.y = fmaf(xi, pos ? up.y : un.y, pos ? cp.y : cn.y);
    o.z = fmaf(xi, pos ? up.z : un.z, pos ? cp.z : cn.z);
    o.w = fmaf(xi, pos ? up.w : un.w, pos ? cp.w : cn.w);
    floatx4* dst = (floatx4*)(out + (size_t)(r0 + r) * DM) + t;
    __builtin_nontemporal_store(o, dst);
  }
}

extern "C" void kernel_launch(void* const* d_in, const int* in_sizes, int n_in,
                              void* d_out, int out_size, void* d_ws, size_t ws_size,
                              hipStream_t stream) {
  const float* psiQ = (const float*)d_in[0];
  const float* psiK = (const float*)d_in[1];
  const float* psiV = (const float*)d_in[2];
  const float* W1 = (const float*)d_in[3];
  const float* b1 = (const float*)d_in[4];
  const float* W2 = (const float*)d_in[5];
  const float* b2 = (const float*)d_in[6];
  float* out = (float*)d_out;
  float* ws = (float*)d_ws;

  qac_prep<<<NPBLK + NROWS / 16, 256, 0, stream>>>(psiQ, psiK, psiV, W1, b1,
                                                   W2, b2, ws, out);
  qac_stream<<<NROWS / 64, 256, 0, stream>>>(ws, out);
}